// Round 4
// baseline (453.014 us; speedup 1.0000x reference)
//
#include <hip/hip_runtime.h>
#include <hip/hip_fp16.h>
#include <cstdint>

#define LRELU(a) ((a) > 0.f ? (a) : 0.2f * (a))
#define BBITS 9                      // 512 nodes per bucket
#define BSZ   (1 << BBITS)
#define MAXB  256                    // max buckets (N=100000 -> 196)

// ---------------- K1: bucket histogram + edge-type histogram ----------------
__global__ __launch_bounds__(256) void k1_bucket_hist(const int* __restrict__ ei,
                                                      const int* __restrict__ ety, int E,
                                                      int* __restrict__ bcount,
                                                      int* __restrict__ counts10) {
    __shared__ int lh[MAXB];
    __shared__ int lt[16];
    int t = threadIdx.x;
    for (int i = t; i < MAXB; i += 256) lh[i] = 0;
    if (t < 16) lt[t] = 0;
    __syncthreads();
    int base = blockIdx.x * 4096;
    int cnt = min(4096, E - base);
    for (int i = t; i < cnt; i += 256) {
        atomicAdd(&lh[ei[E + base + i] >> BBITS], 1);
        atomicAdd(&lt[ety[base + i]], 1);
    }
    __syncthreads();
    for (int i = t; i < MAXB; i += 256) if (lh[i]) atomicAdd(&bcount[i], lh[i]);
    if (t < 16 && lt[t]) atomicAdd(&counts10[t], lt[t]);
}

// ---------------- K2: scan bucket counts (one block) ----------------
__global__ __launch_bounds__(256) void k2_scan(const int* __restrict__ bcount, int NB,
                                               int* __restrict__ bbase,
                                               int* __restrict__ bcursor,
                                               int* __restrict__ rowptr, int N, int E) {
    __shared__ int sc[256], orig[256];
    int t = threadIdx.x;
    int v = (t < NB) ? bcount[t] : 0;
    orig[t] = v;
    sc[t] = v;
    __syncthreads();
    for (int off = 1; off < 256; off <<= 1) {
        int a = (t >= off) ? sc[t - off] : 0;
        __syncthreads();
        sc[t] += a;
        __syncthreads();
    }
    int ex = sc[t] - orig[t];
    bbase[t] = ex;
    bcursor[t] = ex;
    if (t == 0) rowptr[N] = E;
}

// ---------------- K3: coarse-bucket scatter with chunked coalesced append ----------------
__global__ __launch_bounds__(256) void k3_bucket_scatter(const int* __restrict__ ei,
                                                         const int* __restrict__ ety, int E,
                                                         int* __restrict__ bcursor,
                                                         int* __restrict__ staging) {
    __shared__ int ent[4096];
    __shared__ unsigned char ebb[4096];
    __shared__ int lh[MAXB], lstart[MAXB], lcur[MAXB], cbase[MAXB], sc[MAXB];
    int t = threadIdx.x;
    lh[t] = 0;
    __syncthreads();
    int base = blockIdx.x * 4096;
    int cnt = min(4096, E - base);
    for (int i = t; i < cnt; i += 256) atomicAdd(&lh[ei[E + base + i] >> BBITS], 1);
    __syncthreads();
    sc[t] = lh[t];
    __syncthreads();
    for (int off = 1; off < 256; off <<= 1) {
        int a = (t >= off) ? sc[t - off] : 0;
        __syncthreads();
        sc[t] += a;
        __syncthreads();
    }
    lstart[t] = sc[t] - lh[t];
    int c = lh[t];
    cbase[t] = c ? atomicAdd(&bcursor[t], c) : 0;
    lcur[t] = sc[t] - lh[t];
    __syncthreads();
    for (int i = t; i < cnt; i += 256) {
        int s = ei[base + i], d = ei[E + base + i], ty = ety[base + i];
        int b = d >> BBITS;
        int pos = atomicAdd(&lcur[b], 1);
        ent[pos] = s | (ty << 17) | ((d & (BSZ - 1)) << 21);
        ebb[pos] = (unsigned char)b;
    }
    __syncthreads();
    for (int i = t; i < cnt; i += 256) {
        int b = ebb[i];
        staging[cbase[b] + (i - lstart[b])] = ent[i];
    }
}

// ---------------- K4: per-bucket CSR build ----------------
__global__ __launch_bounds__(512) void k4_bucket_build(const int* __restrict__ bbase,
                                                       const int* __restrict__ staging, int N,
                                                       int* __restrict__ rowptr,
                                                       int* __restrict__ packed) {
    __shared__ int lcnt[BSZ], lsc[BSZ], lcur[BSZ];
    int b = blockIdx.x;
    int t = threadIdx.x;
    int base = bbase[b], cnt = bbase[b + 1] - base;
    int n0 = b << BBITS;
    lcnt[t] = 0;
    __syncthreads();
    for (int i = t; i < cnt; i += 512) atomicAdd(&lcnt[staging[base + i] >> 21], 1);
    __syncthreads();
    lsc[t] = lcnt[t];
    __syncthreads();
    for (int off = 1; off < BSZ; off <<= 1) {
        int a = (t >= off) ? lsc[t - off] : 0;
        __syncthreads();
        lsc[t] += a;
        __syncthreads();
    }
    int lstart = lsc[t] - lcnt[t];
    lcur[t] = lstart;
    int node = n0 + t;
    if (node < N) rowptr[node] = base + lstart;
    __syncthreads();
    for (int i = t; i < cnt; i += 512) {
        int entry = staging[base + i];
        int pos = atomicAdd(&lcur[entry >> 21], 1);
        packed[base + pos] = entry & 0x1FFFFF;
    }
}

// ---------------- per-edge-type attention-logit table ----------------
__global__ void alphaE_kernel(const float* __restrict__ emb,
                              const float* __restrict__ w0, const float* __restrict__ ae0,
                              const float* __restrict__ w1, const float* __restrict__ ae1,
                              const int* __restrict__ counts10, int E,
                              float* __restrict__ alphaE) {
    int t = threadIdx.x;
    __shared__ float tmp[88];
    if (t < 80) {
        int l = t / 40, r = t % 40, ty = r >> 2, h = r & 3;
        const float* w = l ? w1 : w0;
        const float* ae = l ? ae1 : ae0;
        int C = l ? 8 : 16;
        const float* ev = emb + ty * 16;
        float val = 0.f;
        for (int c = 0; c < C; ++c) {
            const float* wr = w + (h * C + c) * 16;
            float s = 0.f;
            for (int d = 0; d < 16; ++d) s += wr[d] * ev[d];
            val += s * ae[h * C + c];
        }
        tmp[l * 44 + ty * 4 + h] = val;
        alphaE[l * 44 + ty * 4 + h] = val;
    }
    __syncthreads();
    if (t < 8) {
        int l = t >> 2, h = t & 3;
        float s = 0.f;
        for (int ty = 0; ty < 10; ++ty) s += (float)counts10[ty] * tmp[l * 44 + ty * 4 + h];
        alphaE[l * 44 + 40 + h] = s / (float)E;
    }
}

// ---------------- h = x @ W^T, output fp16 HEAD-MAJOR [H][N][C] ----------------
template <int OUT, int C>
__global__ __launch_bounds__(256) void gemm_kernel(const float* __restrict__ x,
                                                   const float* __restrict__ W, int N,
                                                   __half* __restrict__ out) {
    __shared__ float wt[64 * (OUT + 1)];
    __shared__ float xs[32 * 64];
    int t = threadIdx.x;
    for (int idx = t; idx < OUT * 64; idx += 256) {
        int j = idx >> 6, k = idx & 63;
        wt[k * (OUT + 1) + j] = W[idx];
    }
    int rowbase = blockIdx.x * 32;
    int nrows = min(32, N - rowbase);
    for (int idx = t; idx < nrows * 64; idx += 256) xs[idx] = x[rowbase * 64 + idx];
    __syncthreads();
    int j = t % OUT;
    int rg = t / OUT;
    const int NG = 256 / OUT;
    int hd = j / C, c = j & (C - 1);
    for (int r = rg; r < nrows; r += NG) {
        float acc = 0.f;
        const float* xr = xs + r * 64;
#pragma unroll
        for (int k = 0; k < 64; ++k) acc += xr[k] * wt[k * (OUT + 1) + j];
        out[((size_t)hd * N + rowbase + r) * C + c] = __float2half(acc);
    }
}

// ---------------- per-(head,node) attention scores; h,[ssrc,sdst] head-major ----------------
template <int C>
__global__ __launch_bounds__(256) void score_kernel(const __half* __restrict__ h,
                                                    const float* __restrict__ asrc,
                                                    const float* __restrict__ adst, int N,
                                                    float* __restrict__ ssrc,
                                                    float* __restrict__ sdst) {
    int t = blockIdx.x * 256 + threadIdx.x;   // t = hd*N + node (flat [H][N])
    if (t >= N * 4) return;
    int hd = t / N;
    const __half2* hr = (const __half2*)(h + (size_t)t * C);
    float s1 = 0.f, s2 = 0.f;
#pragma unroll
    for (int c2 = 0; c2 < C / 2; ++c2) {
        float2 v = __half22float2(hr[c2]);
        s1 += v.x * asrc[hd * C + c2 * 2] + v.y * asrc[hd * C + c2 * 2 + 1];
        s2 += v.x * adst[hd * C + c2 * 2] + v.y * adst[hd * C + c2 * 2 + 1];
    }
    ssrc[t] = s1;
    sdst[t] = s2;
}

__device__ inline void fma_h8(float* acc, float4 v, float ex) {
    const __half2* h2 = (const __half2*)&v;
#pragma unroll
    for (int i = 0; i < 4; ++i) {
        float2 f = __half22float2(h2[i]);
        acc[2 * i]     += ex * f.x;
        acc[2 * i + 1] += ex * f.y;
    }
}

// ---------------- per-(head,node) online-softmax aggregate ----------------
// Block b: xcd = b&7 pins this block (round-robin dispatch) -> head = xcd>>1,
// so each XCD's L2 caches exactly one head's slice (3.6 MB < 4 MB).
template <int C, bool RELU>
__global__ __launch_bounds__(256) void agg_kernel(const int* __restrict__ rowptr,
                                                  const int* __restrict__ packed,
                                                  const __half* __restrict__ hmat,
                                                  const float* __restrict__ ssrc,
                                                  const float* __restrict__ sdst,
                                                  const float* __restrict__ alphaE,
                                                  const float* __restrict__ bias, int N,
                                                  float* __restrict__ out) {
    int b = blockIdx.x;
    int xcd = b & 7;
    int hd = xcd >> 1;
    int chunk = (b >> 3) * 2 + (xcd & 1);
    __shared__ float aEh[11];
    if (threadIdx.x < 11) aEh[threadIdx.x] = alphaE[threadIdx.x * 4 + hd];  // [11][4] table
    __syncthreads();
    int node = chunk * 256 + threadIdx.x;
    if (node >= N) return;
    int g0i = hd * N + node;
    int beg = rowptr[node], end = rowptr[node + 1];
    float sd = sdst[g0i];
    float m = LRELU(ssrc[g0i] + sd + aEh[10]);
    float denom = 1.f;
    float acc[C];
    {
        const float4* hn = (const float4*)(hmat + (size_t)g0i * C);
#pragma unroll
        for (int c = 0; c < C; ++c) acc[c] = 0.f;
#pragma unroll
        for (int i = 0; i < C / 8; ++i) fma_h8(acc + 8 * i, hn[i], 1.f);
    }
    int k = beg;
    for (; k + 2 <= end; k += 2) {
        int p0 = packed[k], p1 = packed[k + 1];
        int s0 = hd * N + (p0 & 131071), ty0 = (p0 >> 17) & 15;
        int s1 = hd * N + (p1 & 131071), ty1 = (p1 >> 17) & 15;
        float v0 = ssrc[s0], v1 = ssrc[s1];
        const float4* g0 = (const float4*)(hmat + (size_t)s0 * C);
        const float4* g1 = (const float4*)(hmat + (size_t)s1 * C);
        float4 r0[C / 8], r1[C / 8];
#pragma unroll
        for (int i = 0; i < C / 8; ++i) { r0[i] = g0[i]; r1[i] = g1[i]; }
        float a0 = LRELU(v0 + sd + aEh[ty0]);
        float a1 = LRELU(v1 + sd + aEh[ty1]);
        float mn = fmaxf(a0, a1);
        if (mn > m) {
            float r = __expf(m - mn);
            denom *= r;
#pragma unroll
            for (int c = 0; c < C; ++c) acc[c] *= r;
            m = mn;
        }
        float e0 = __expf(a0 - m), e1 = __expf(a1 - m);
        denom += e0 + e1;
#pragma unroll
        for (int i = 0; i < C / 8; ++i) { fma_h8(acc + 8 * i, r0[i], e0); fma_h8(acc + 8 * i, r1[i], e1); }
    }
    if (k < end) {
        int p0 = packed[k];
        int s0 = hd * N + (p0 & 131071), ty0 = (p0 >> 17) & 15;
        float v0 = ssrc[s0];
        const float4* g0 = (const float4*)(hmat + (size_t)s0 * C);
        float4 r0[C / 8];
#pragma unroll
        for (int i = 0; i < C / 8; ++i) r0[i] = g0[i];
        float a0 = LRELU(v0 + sd + aEh[ty0]);
        if (a0 > m) {
            float r = __expf(m - a0);
            denom *= r;
#pragma unroll
            for (int c = 0; c < C; ++c) acc[c] *= r;
            m = a0;
        }
        float e0 = __expf(a0 - m);
        denom += e0;
#pragma unroll
        for (int i = 0; i < C / 8; ++i) fma_h8(acc + 8 * i, r0[i], e0);
    }
    float inv = 1.f / denom;
    float* op = out + (size_t)node * (4 * C) + hd * C;
#pragma unroll
    for (int c = 0; c < C; ++c) {
        float o = fmaf(acc[c], inv, bias[hd * C + c]);
        if (RELU) o = fmaxf(o, 0.f);
        op[c] = o;
    }
}

extern "C" void kernel_launch(void* const* d_in, const int* in_sizes, int n_in,
                              void* d_out, int out_size, void* d_ws, size_t ws_size,
                              hipStream_t stream) {
    const float* x    = (const float*)d_in[0];
    const int*   ei   = (const int*)d_in[1];
    const int*   ety  = (const int*)d_in[2];
    const float* emb  = (const float*)d_in[3];
    const float* w0   = (const float*)d_in[4];
    const float* as0  = (const float*)d_in[5];
    const float* ad0  = (const float*)d_in[6];
    const float* we0  = (const float*)d_in[7];
    const float* ae0  = (const float*)d_in[8];
    const float* b0   = (const float*)d_in[9];
    const float* w1   = (const float*)d_in[10];
    const float* as1  = (const float*)d_in[11];
    const float* ad1  = (const float*)d_in[12];
    const float* we1  = (const float*)d_in[13];
    const float* ae1  = (const float*)d_in[14];
    const float* b1   = (const float*)d_in[15];

    const int N = in_sizes[0] / 64;
    const int E = in_sizes[1] / 2;
    const int NB = (N + BSZ - 1) >> BBITS;

    char* ws = (char*)d_ws;
    size_t o = 0;
    auto alloc = [&](size_t bytes) { size_t r = o; o = (o + bytes + 255) & ~(size_t)255; return r; };
    size_t o_bcount   = alloc(4 * 260);
    size_t o_bbase    = alloc(4 * 260);
    size_t o_bcursor  = alloc(4 * 260);
    size_t o_counts10 = alloc(64);
    size_t o_alphaE   = alloc(4 * 88);
    size_t o_rowptr   = alloc((size_t)4 * (N + 1));
    size_t o_staging  = alloc((size_t)4 * E);
    size_t o_packed   = alloc((size_t)4 * E);
    size_t o_h0       = alloc((size_t)2 * N * 64);   // fp16 h, head-major
    size_t o_x1       = alloc((size_t)4 * N * 64);
    size_t o_ssrc     = alloc((size_t)4 * N * 4);
    size_t o_sdst     = alloc((size_t)4 * N * 4);
    (void)ws_size;

    int*    bcount   = (int*)(ws + o_bcount);
    int*    bbase    = (int*)(ws + o_bbase);
    int*    bcursor  = (int*)(ws + o_bcursor);
    int*    counts10 = (int*)(ws + o_counts10);
    float*  alphaE   = (float*)(ws + o_alphaE);
    int*    rowptr   = (int*)(ws + o_rowptr);
    int*    staging  = (int*)(ws + o_staging);
    int*    packed   = (int*)(ws + o_packed);
    __half* h0       = (__half*)(ws + o_h0);
    float*  x1       = (float*)(ws + o_x1);
    float*  ssrc     = (float*)(ws + o_ssrc);
    float*  sdst     = (float*)(ws + o_sdst);
    float*  outp     = (float*)d_out;

    hipMemsetAsync(bcount, 0, 4 * 260, stream);
    hipMemsetAsync(counts10, 0, 64, stream);

    int egrid = (E + 4095) / 4096;
    k1_bucket_hist<<<egrid, 256, 0, stream>>>(ei, ety, E, bcount, counts10);
    alphaE_kernel<<<1, 128, 0, stream>>>(emb, we0, ae0, we1, ae1, counts10, E, alphaE);
    k2_scan<<<1, 256, 0, stream>>>(bcount, NB, bbase, bcursor, rowptr, N, E);
    k3_bucket_scatter<<<egrid, 256, 0, stream>>>(ei, ety, E, bcursor, staging);
    k4_bucket_build<<<NB, 512, 0, stream>>>(bbase, staging, N, rowptr, packed);

    int ngrid32 = (N + 31) / 32;
    int tgrid = (N * 4 + 255) / 256;
    int nchunk = (N + 255) / 256;
    int agg_grid = ((nchunk + 1) / 2) * 8;

    // Layer 0: in=64, H=4, C=16
    gemm_kernel<64, 16><<<ngrid32, 256, 0, stream>>>(x, w0, N, h0);
    score_kernel<16><<<tgrid, 256, 0, stream>>>(h0, as0, ad0, N, ssrc, sdst);
    agg_kernel<16, true><<<agg_grid, 256, 0, stream>>>(rowptr, packed, h0, ssrc, sdst,
                                                       alphaE, b0, N, x1);
    // Layer 1: in=64, H=4, C=8
    gemm_kernel<32, 8><<<ngrid32, 256, 0, stream>>>(x1, w1, N, h0);
    score_kernel<8><<<tgrid, 256, 0, stream>>>(h0, as1, ad1, N, ssrc, sdst);
    agg_kernel<8, false><<<agg_grid, 256, 0, stream>>>(rowptr, packed, h0, ssrc, sdst,
                                                       alphaE + 44, b1, N, outp);
}

// Round 6
// 329.392 us; speedup vs baseline: 1.3753x; 1.3753x over previous
//
#include <hip/hip_runtime.h>
#include <hip/hip_fp16.h>
#include <cstdint>

#define LRELU(a) ((a) > 0.f ? (a) : 0.2f * (a))
#define BBITS 9                      // 512 nodes per bucket
#define BSZ   (1 << BBITS)
#define MAXB  256                    // max buckets (N=100000 -> 196)

typedef float cfloat4 __attribute__((ext_vector_type(4)));   // clang vector: ok for nontemporal builtins

// ---------------- K1: bucket histogram + edge-type histogram ----------------
__global__ __launch_bounds__(256) void k1_bucket_hist(const int* __restrict__ ei,
                                                      const int* __restrict__ ety, int E,
                                                      int* __restrict__ bcount,
                                                      int* __restrict__ counts10) {
    __shared__ int lh[MAXB];
    __shared__ int lt[16];
    int t = threadIdx.x;
    for (int i = t; i < MAXB; i += 256) lh[i] = 0;
    if (t < 16) lt[t] = 0;
    __syncthreads();
    int base = blockIdx.x * 4096;
    int cnt = min(4096, E - base);
    for (int i = t; i < cnt; i += 256) {
        atomicAdd(&lh[ei[E + base + i] >> BBITS], 1);
        atomicAdd(&lt[ety[base + i]], 1);
    }
    __syncthreads();
    for (int i = t; i < MAXB; i += 256) if (lh[i]) atomicAdd(&bcount[i], lh[i]);
    if (t < 16 && lt[t]) atomicAdd(&counts10[t], lt[t]);
}

// ---------------- K2: scan bucket counts (one block) ----------------
__global__ __launch_bounds__(256) void k2_scan(const int* __restrict__ bcount, int NB,
                                               int* __restrict__ bbase,
                                               int* __restrict__ bcursor,
                                               int* __restrict__ rowptr, int N, int E) {
    __shared__ int sc[256], orig[256];
    int t = threadIdx.x;
    int v = (t < NB) ? bcount[t] : 0;
    orig[t] = v;
    sc[t] = v;
    __syncthreads();
    for (int off = 1; off < 256; off <<= 1) {
        int a = (t >= off) ? sc[t - off] : 0;
        __syncthreads();
        sc[t] += a;
        __syncthreads();
    }
    int ex = sc[t] - orig[t];
    bbase[t] = ex;
    bcursor[t] = ex;
    if (t == 0) rowptr[N] = E;
}

// ---------------- K3: coarse-bucket scatter with chunked coalesced append ----------------
__global__ __launch_bounds__(256) void k3_bucket_scatter(const int* __restrict__ ei,
                                                         const int* __restrict__ ety, int E,
                                                         int* __restrict__ bcursor,
                                                         int* __restrict__ staging) {
    __shared__ int ent[4096];
    __shared__ unsigned char ebb[4096];
    __shared__ int lh[MAXB], lstart[MAXB], lcur[MAXB], cbase[MAXB], sc[MAXB];
    int t = threadIdx.x;
    lh[t] = 0;
    __syncthreads();
    int base = blockIdx.x * 4096;
    int cnt = min(4096, E - base);
    for (int i = t; i < cnt; i += 256) atomicAdd(&lh[ei[E + base + i] >> BBITS], 1);
    __syncthreads();
    sc[t] = lh[t];
    __syncthreads();
    for (int off = 1; off < 256; off <<= 1) {
        int a = (t >= off) ? sc[t - off] : 0;
        __syncthreads();
        sc[t] += a;
        __syncthreads();
    }
    lstart[t] = sc[t] - lh[t];
    int c = lh[t];
    cbase[t] = c ? atomicAdd(&bcursor[t], c) : 0;
    lcur[t] = sc[t] - lh[t];
    __syncthreads();
    for (int i = t; i < cnt; i += 256) {
        int s = ei[base + i], d = ei[E + base + i], ty = ety[base + i];
        int b = d >> BBITS;
        int pos = atomicAdd(&lcur[b], 1);
        ent[pos] = s | (ty << 17) | ((d & (BSZ - 1)) << 21);
        ebb[pos] = (unsigned char)b;
    }
    __syncthreads();
    for (int i = t; i < cnt; i += 256) {
        int b = ebb[i];
        staging[cbase[b] + (i - lstart[b])] = ent[i];
    }
}

// ---------------- K4: per-bucket CSR build ----------------
__global__ __launch_bounds__(512) void k4_bucket_build(const int* __restrict__ bbase,
                                                       const int* __restrict__ staging, int N,
                                                       int* __restrict__ rowptr,
                                                       int* __restrict__ packed) {
    __shared__ int lcnt[BSZ], lsc[BSZ], lcur[BSZ];
    int b = blockIdx.x;
    int t = threadIdx.x;
    int base = bbase[b], cnt = bbase[b + 1] - base;
    int n0 = b << BBITS;
    lcnt[t] = 0;
    __syncthreads();
    for (int i = t; i < cnt; i += 512) atomicAdd(&lcnt[staging[base + i] >> 21], 1);
    __syncthreads();
    lsc[t] = lcnt[t];
    __syncthreads();
    for (int off = 1; off < BSZ; off <<= 1) {
        int a = (t >= off) ? lsc[t - off] : 0;
        __syncthreads();
        lsc[t] += a;
        __syncthreads();
    }
    int lstart = lsc[t] - lcnt[t];
    lcur[t] = lstart;
    int node = n0 + t;
    if (node < N) rowptr[node] = base + lstart;
    __syncthreads();
    for (int i = t; i < cnt; i += 512) {
        int entry = staging[base + i];
        int pos = atomicAdd(&lcur[entry >> 21], 1);
        packed[base + pos] = entry & 0x1FFFFF;
    }
}

// ---------------- per-edge-type attention-logit table ----------------
__global__ void alphaE_kernel(const float* __restrict__ emb,
                              const float* __restrict__ w0, const float* __restrict__ ae0,
                              const float* __restrict__ w1, const float* __restrict__ ae1,
                              const int* __restrict__ counts10, int E,
                              float* __restrict__ alphaE) {
    int t = threadIdx.x;
    __shared__ float tmp[88];
    if (t < 80) {
        int l = t / 40, r = t % 40, ty = r >> 2, h = r & 3;
        const float* w = l ? w1 : w0;
        const float* ae = l ? ae1 : ae0;
        int C = l ? 8 : 16;
        const float* ev = emb + ty * 16;
        float val = 0.f;
        for (int c = 0; c < C; ++c) {
            const float* wr = w + (h * C + c) * 16;
            float s = 0.f;
            for (int d = 0; d < 16; ++d) s += wr[d] * ev[d];
            val += s * ae[h * C + c];
        }
        tmp[l * 44 + ty * 4 + h] = val;
        alphaE[l * 44 + ty * 4 + h] = val;
    }
    __syncthreads();
    if (t < 8) {
        int l = t >> 2, h = t & 3;
        float s = 0.f;
        for (int ty = 0; ty < 10; ++ty) s += (float)counts10[ty] * tmp[l * 44 + ty * 4 + h];
        alphaE[l * 44 + 40 + h] = s / (float)E;
    }
}

// ---------------- h = x @ W^T, output fp16 node-major [N][OUT] ----------------
template <int OUT>
__global__ __launch_bounds__(256) void gemm_kernel(const float* __restrict__ x,
                                                   const float* __restrict__ W, int N,
                                                   __half* __restrict__ out) {
    __shared__ float wt[64 * (OUT + 1)];
    __shared__ float xs[32 * 64];
    int t = threadIdx.x;
    for (int idx = t; idx < OUT * 64; idx += 256) {
        int j = idx >> 6, k = idx & 63;
        wt[k * (OUT + 1) + j] = W[idx];
    }
    int rowbase = blockIdx.x * 32;
    int nrows = min(32, N - rowbase);
    for (int idx = t; idx < nrows * 64; idx += 256) xs[idx] = x[rowbase * 64 + idx];
    __syncthreads();
    int j = t % OUT;
    int rg = t / OUT;
    const int NG = 256 / OUT;
    for (int r = rg; r < nrows; r += NG) {
        float acc = 0.f;
        const float* xr = xs + r * 64;
#pragma unroll
        for (int k = 0; k < 64; ++k) acc += xr[k] * wt[k * (OUT + 1) + j];
        out[(size_t)(rowbase + r) * OUT + j] = __float2half(acc);
    }
}

// ---------------- per-(node,head) attention scores (node-major) ----------------
template <int C>
__global__ __launch_bounds__(256) void score_kernel(const __half* __restrict__ h,
                                                    const float* __restrict__ asrc,
                                                    const float* __restrict__ adst, int N,
                                                    float* __restrict__ ssrc,
                                                    float* __restrict__ sdst) {
    int t = blockIdx.x * 256 + threadIdx.x;   // t = node*4 + hd
    if (t >= N * 4) return;
    int hd = t & 3;
    const __half2* hr = (const __half2*)(h + (size_t)t * C);
    float s1 = 0.f, s2 = 0.f;
#pragma unroll
    for (int c2 = 0; c2 < C / 2; ++c2) {
        float2 v = __half22float2(hr[c2]);
        s1 += v.x * asrc[hd * C + c2 * 2] + v.y * asrc[hd * C + c2 * 2 + 1];
        s2 += v.x * adst[hd * C + c2 * 2] + v.y * adst[hd * C + c2 * 2 + 1];
    }
    ssrc[t] = s1;
    sdst[t] = s2;
}

__device__ inline void fma_h8(float* acc, float4 v, float ex) {
    const __half2* h2 = (const __half2*)&v;
#pragma unroll
    for (int i = 0; i < 4; ++i) {
        float2 f = __half22float2(h2[i]);
        acc[2 * i]     += ex * f.x;
        acc[2 * i + 1] += ex * f.y;
    }
}

// ---------------- online-softmax aggregate: TPN threads per node, 8 fp16 ch each ----
// TPN=8 for C=16 (2 threads/head), TPN=4 for C=8 (1 thread/head). Per-edge each
// thread gathers one 16B chunk; group of TPN covers the full 4*C*2B contiguous row.
template <int C, int TPN, bool RELU>
__global__ __launch_bounds__(256) void agg_kernel(const int* __restrict__ rowptr,
                                                  const int* __restrict__ packed,
                                                  const __half* __restrict__ hmat,
                                                  const float* __restrict__ ssrc,
                                                  const float* __restrict__ sdst,
                                                  const float* __restrict__ alphaE,
                                                  const float* __restrict__ bias, int N,
                                                  float* __restrict__ out) {
    __shared__ float aE[44];
    if (threadIdx.x < 44) aE[threadIdx.x] = alphaE[threadIdx.x];
    __syncthreads();
    int t = blockIdx.x * 256 + threadIdx.x;
    if (t >= N * TPN) return;
    const int HALVES = TPN / 4;                 // 16B chunks per head row
    int node = t / TPN;
    int sub  = t % TPN;
    int hd   = sub / HALVES;
    int off  = hd * C + (sub % HALVES) * 8;     // fp16 offset within node row
    const int ROW = 4 * C;                      // fp16 per node row
    int beg = rowptr[node], end = rowptr[node + 1];
    float sd = sdst[node * 4 + hd];
    float m = LRELU(ssrc[node * 4 + hd] + sd + aE[40 + hd]);
    float denom = 1.f;
    float acc[8];
    {
        float4 sv = *(const float4*)(hmat + (size_t)node * ROW + off);
#pragma unroll
        for (int c = 0; c < 8; ++c) acc[c] = 0.f;
        fma_h8(acc, sv, 1.f);
    }
    int k = beg;
    for (; k + 4 <= end; k += 4) {
        int p0 = __builtin_nontemporal_load(&packed[k]);
        int p1 = __builtin_nontemporal_load(&packed[k + 1]);
        int p2 = __builtin_nontemporal_load(&packed[k + 2]);
        int p3 = __builtin_nontemporal_load(&packed[k + 3]);
        int n0 = p0 & 131071, n1 = p1 & 131071, n2 = p2 & 131071, n3 = p3 & 131071;
        float v0 = ssrc[n0 * 4 + hd], v1 = ssrc[n1 * 4 + hd];
        float v2 = ssrc[n2 * 4 + hd], v3 = ssrc[n3 * 4 + hd];
        float4 r0 = *(const float4*)(hmat + (size_t)n0 * ROW + off);
        float4 r1 = *(const float4*)(hmat + (size_t)n1 * ROW + off);
        float4 r2 = *(const float4*)(hmat + (size_t)n2 * ROW + off);
        float4 r3 = *(const float4*)(hmat + (size_t)n3 * ROW + off);
        float a0 = LRELU(v0 + sd + aE[((p0 >> 17) & 15) * 4 + hd]);
        float a1 = LRELU(v1 + sd + aE[((p1 >> 17) & 15) * 4 + hd]);
        float a2 = LRELU(v2 + sd + aE[((p2 >> 17) & 15) * 4 + hd]);
        float a3 = LRELU(v3 + sd + aE[((p3 >> 17) & 15) * 4 + hd]);
        float mn = fmaxf(fmaxf(a0, a1), fmaxf(a2, a3));
        if (mn > m) {
            float r = __expf(m - mn);
            denom *= r;
#pragma unroll
            for (int c = 0; c < 8; ++c) acc[c] *= r;
            m = mn;
        }
        float e0 = __expf(a0 - m), e1 = __expf(a1 - m);
        float e2 = __expf(a2 - m), e3 = __expf(a3 - m);
        denom += (e0 + e1) + (e2 + e3);
        fma_h8(acc, r0, e0);
        fma_h8(acc, r1, e1);
        fma_h8(acc, r2, e2);
        fma_h8(acc, r3, e3);
    }
    for (; k < end; ++k) {
        int p0 = __builtin_nontemporal_load(&packed[k]);
        int n0 = p0 & 131071;
        float v0 = ssrc[n0 * 4 + hd];
        float4 r0 = *(const float4*)(hmat + (size_t)n0 * ROW + off);
        float a0 = LRELU(v0 + sd + aE[((p0 >> 17) & 15) * 4 + hd]);
        if (a0 > m) {
            float r = __expf(m - a0);
            denom *= r;
#pragma unroll
            for (int c = 0; c < 8; ++c) acc[c] *= r;
            m = a0;
        }
        float e0 = __expf(a0 - m);
        denom += e0;
        fma_h8(acc, r0, e0);
    }
    float inv = 1.f / denom;
    cfloat4 o0, o1;
#pragma unroll
    for (int c = 0; c < 4; ++c) {
        float a = fmaf(acc[c], inv, bias[off + c]);
        float b = fmaf(acc[c + 4], inv, bias[off + c + 4]);
        if (RELU) { a = fmaxf(a, 0.f); b = fmaxf(b, 0.f); }
        o0[c] = a;
        o1[c] = b;
    }
    cfloat4* op = (cfloat4*)(out + (size_t)node * ROW + off);
    __builtin_nontemporal_store(o0, op);
    __builtin_nontemporal_store(o1, op + 1);
}

extern "C" void kernel_launch(void* const* d_in, const int* in_sizes, int n_in,
                              void* d_out, int out_size, void* d_ws, size_t ws_size,
                              hipStream_t stream) {
    const float* x    = (const float*)d_in[0];
    const int*   ei   = (const int*)d_in[1];
    const int*   ety  = (const int*)d_in[2];
    const float* emb  = (const float*)d_in[3];
    const float* w0   = (const float*)d_in[4];
    const float* as0  = (const float*)d_in[5];
    const float* ad0  = (const float*)d_in[6];
    const float* we0  = (const float*)d_in[7];
    const float* ae0  = (const float*)d_in[8];
    const float* b0   = (const float*)d_in[9];
    const float* w1   = (const float*)d_in[10];
    const float* as1  = (const float*)d_in[11];
    const float* ad1  = (const float*)d_in[12];
    const float* we1  = (const float*)d_in[13];
    const float* ae1  = (const float*)d_in[14];
    const float* b1   = (const float*)d_in[15];

    const int N = in_sizes[0] / 64;
    const int E = in_sizes[1] / 2;
    const int NB = (N + BSZ - 1) >> BBITS;

    char* ws = (char*)d_ws;
    size_t o = 0;
    auto alloc = [&](size_t bytes) { size_t r = o; o = (o + bytes + 255) & ~(size_t)255; return r; };
    size_t o_bcount   = alloc(4 * 260);
    size_t o_bbase    = alloc(4 * 260);
    size_t o_bcursor  = alloc(4 * 260);
    size_t o_counts10 = alloc(64);
    size_t o_alphaE   = alloc(4 * 88);
    size_t o_rowptr   = alloc((size_t)4 * (N + 1));
    size_t o_staging  = alloc((size_t)4 * E);
    size_t o_packed   = alloc((size_t)4 * E);
    size_t o_h0       = alloc((size_t)2 * N * 64);   // fp16 h, node-major
    size_t o_x1       = alloc((size_t)4 * N * 64);
    size_t o_ssrc     = alloc((size_t)4 * N * 4);
    size_t o_sdst     = alloc((size_t)4 * N * 4);
    (void)ws_size;

    int*    bcount   = (int*)(ws + o_bcount);
    int*    bbase    = (int*)(ws + o_bbase);
    int*    bcursor  = (int*)(ws + o_bcursor);
    int*    counts10 = (int*)(ws + o_counts10);
    float*  alphaE   = (float*)(ws + o_alphaE);
    int*    rowptr   = (int*)(ws + o_rowptr);
    int*    staging  = (int*)(ws + o_staging);
    int*    packed   = (int*)(ws + o_packed);
    __half* h0       = (__half*)(ws + o_h0);
    float*  x1       = (float*)(ws + o_x1);
    float*  ssrc     = (float*)(ws + o_ssrc);
    float*  sdst     = (float*)(ws + o_sdst);
    float*  outp     = (float*)d_out;

    hipMemsetAsync(bcount, 0, 4 * 260, stream);
    hipMemsetAsync(counts10, 0, 64, stream);

    int egrid = (E + 4095) / 4096;
    k1_bucket_hist<<<egrid, 256, 0, stream>>>(ei, ety, E, bcount, counts10);
    alphaE_kernel<<<1, 128, 0, stream>>>(emb, we0, ae0, we1, ae1, counts10, E, alphaE);
    k2_scan<<<1, 256, 0, stream>>>(bcount, NB, bbase, bcursor, rowptr, N, E);
    k3_bucket_scatter<<<egrid, 256, 0, stream>>>(ei, ety, E, bcursor, staging);
    k4_bucket_build<<<NB, 512, 0, stream>>>(bbase, staging, N, rowptr, packed);

    int ngrid32 = (N + 31) / 32;
    int tgrid = (N * 4 + 255) / 256;
    int agg_grid0 = (N * 8 + 255) / 256;   // TPN=8
    int agg_grid1 = (N * 4 + 255) / 256;   // TPN=4

    // Layer 0: in=64, H=4, C=16
    gemm_kernel<64><<<ngrid32, 256, 0, stream>>>(x, w0, N, h0);
    score_kernel<16><<<tgrid, 256, 0, stream>>>(h0, as0, ad0, N, ssrc, sdst);
    agg_kernel<16, 8, true><<<agg_grid0, 256, 0, stream>>>(rowptr, packed, h0, ssrc, sdst,
                                                           alphaE, b0, N, x1);
    // Layer 1: in=64, H=4, C=8
    gemm_kernel<32><<<ngrid32, 256, 0, stream>>>(x1, w1, N, h0);
    score_kernel<8><<<tgrid, 256, 0, stream>>>(h0, as1, ad1, N, ssrc, sdst);
    agg_kernel<8, 4, false><<<agg_grid1, 256, 0, stream>>>(rowptr, packed, h0, ssrc, sdst,
                                                           alphaE + 44, b1, N, outp);
}

// Round 7
// 325.636 us; speedup vs baseline: 1.3912x; 1.0115x over previous
//
#include <hip/hip_runtime.h>
#include <hip/hip_fp16.h>
#include <cstdint>
#include <type_traits>

#define LRELU(a) ((a) > 0.f ? (a) : 0.2f * (a))
#define BBITS 9                      // 512 nodes per bucket
#define BSZ   (1 << BBITS)
#define MAXB  256                    // max buckets (N=100000 -> 196)
#define SL    8                      // src slices per node (src>>14 -> 0..6 used)

typedef float cfloat4 __attribute__((ext_vector_type(4)));

__device__ inline float ldf(const float* p, int i) { return p[i]; }
__device__ inline float ldf(const __half* p, int i) { return __half2float(p[i]); }

// ---- K1: bucket histogram + type histogram; LAST block: scan + alphaE table ----
__global__ __launch_bounds__(256) void k1_hist_scan(
        const int* __restrict__ ei, const int* __restrict__ ety, int E,
        int* __restrict__ bcount, int* __restrict__ counts10, int* __restrict__ done,
        int NB, int* __restrict__ bbase, int* __restrict__ bcursor,
        int* __restrict__ rowptr, int N,
        const float* __restrict__ emb,
        const float* __restrict__ w0, const float* __restrict__ ae0,
        const float* __restrict__ w1, const float* __restrict__ ae1,
        float* __restrict__ alphaE) {
    __shared__ int lh[MAXB];
    __shared__ int lt[16];
    __shared__ int lastFlag;
    int t = threadIdx.x;
    lh[t] = 0;
    if (t < 16) lt[t] = 0;
    __syncthreads();
    int base = blockIdx.x * 4096;
    int cnt = min(4096, E - base);
    for (int i = t; i < cnt; i += 256) {
        atomicAdd(&lh[ei[E + base + i] >> BBITS], 1);
        atomicAdd(&lt[ety[base + i]], 1);
    }
    __syncthreads();
    if (lh[t]) atomicAdd(&bcount[t], lh[t]);
    if (t < 16 && lt[t]) atomicAdd(&counts10[t], lt[t]);
    __syncthreads();
    if (t == 0) {
        __threadfence();
        int tk = atomicAdd(done, 1);
        lastFlag = (tk == (int)gridDim.x - 1);
    }
    __syncthreads();
    if (!lastFlag) return;
    __threadfence();
    // ---- exclusive scan of bcount (coherent reads via atomicAdd 0) ----
    __shared__ int sc[256], orig[256];
    int v = (t < NB) ? atomicAdd(&bcount[t], 0) : 0;
    orig[t] = v;
    sc[t] = v;
    __syncthreads();
    for (int off = 1; off < 256; off <<= 1) {
        int a = (t >= off) ? sc[t - off] : 0;
        __syncthreads();
        sc[t] += a;
        __syncthreads();
    }
    int ex = sc[t] - orig[t];
    bbase[t] = ex;              // t>=NB: ex == E
    bcursor[t] = ex;
    if (t == 0) rowptr[N] = E;
    // ---- alphaE table [2][11][4] ----
    __shared__ float tmp[88];
    if (t < 80) {
        int l = t / 40, r = t % 40, ty = r >> 2, h = r & 3;
        const float* w = l ? w1 : w0;
        const float* ae = l ? ae1 : ae0;
        int C = l ? 8 : 16;
        const float* ev = emb + ty * 16;
        float val = 0.f;
        for (int c = 0; c < C; ++c) {
            const float* wr = w + (h * C + c) * 16;
            float s = 0.f;
            for (int d = 0; d < 16; ++d) s += wr[d] * ev[d];
            val += s * ae[h * C + c];
        }
        tmp[l * 44 + ty * 4 + h] = val;
        alphaE[l * 44 + ty * 4 + h] = val;
    }
    __syncthreads();
    if (t < 8) {
        int l = t >> 2, h = t & 3;
        float s = 0.f;
        for (int ty = 0; ty < 10; ++ty)
            s += (float)atomicAdd(&counts10[ty], 0) * tmp[l * 44 + ty * 4 + h];
        alphaE[l * 44 + 40 + h] = s / (float)E;
    }
}

// ---- K3: coarse-bucket scatter, single global read, LDS regroup ----
__global__ __launch_bounds__(256) void k3_bucket_scatter(const int* __restrict__ ei,
                                                         const int* __restrict__ ety, int E,
                                                         int* __restrict__ bcursor,
                                                         int* __restrict__ staging) {
    __shared__ int ent[4096], ent2[4096];
    __shared__ unsigned char ebb[4096], ebb2[4096];
    __shared__ int lh[MAXB], lstart[MAXB], lcur[MAXB], cbase[MAXB], sc[MAXB];
    int t = threadIdx.x;
    lh[t] = 0;
    __syncthreads();
    int base = blockIdx.x * 4096;
    int cnt = min(4096, E - base);
    for (int i = t; i < cnt; i += 256) {
        int s = ei[base + i], d = ei[E + base + i], ty = ety[base + i];
        int b = d >> BBITS;
        ent[i] = s | (ty << 17) | ((d & (BSZ - 1)) << 21);
        ebb[i] = (unsigned char)b;
        atomicAdd(&lh[b], 1);
    }
    __syncthreads();
    sc[t] = lh[t];
    __syncthreads();
    for (int off = 1; off < 256; off <<= 1) {
        int a = (t >= off) ? sc[t - off] : 0;
        __syncthreads();
        sc[t] += a;
        __syncthreads();
    }
    lstart[t] = sc[t] - lh[t];
    cbase[t] = lh[t] ? atomicAdd(&bcursor[t], lh[t]) : 0;
    lcur[t] = lstart[t];
    __syncthreads();
    for (int i = t; i < cnt; i += 256) {
        int b = ebb[i];
        int pos = atomicAdd(&lcur[b], 1);
        ent2[pos] = ent[i];
        ebb2[pos] = (unsigned char)b;
    }
    __syncthreads();
    for (int i = t; i < cnt; i += 256) {
        int b = ebb2[i];
        staging[cbase[b] + (i - lstart[b])] = ent2[i];
    }
}

// ---- K4: per-bucket CSR build, edges grouped by (node, src>>14 slice) ----
__global__ __launch_bounds__(512) void k4_bucket_build(const int* __restrict__ bbase,
                                                       const int* __restrict__ staging, int N,
                                                       int* __restrict__ rowptr,
                                                       int* __restrict__ packed) {
    __shared__ int lcnt[BSZ * SL];
    __shared__ int lcur[BSZ * SL];
    __shared__ int tsum[BSZ];
    int b = blockIdx.x;
    int t = threadIdx.x;
    int base = bbase[b], cnt = bbase[b + 1] - base;
    int n0 = b << BBITS;
    for (int i = t; i < BSZ * SL; i += 512) lcnt[i] = 0;
    __syncthreads();
    for (int i = t; i < cnt; i += 512) {
        int e = staging[base + i];
        int node = (e >> 21) & (BSZ - 1);
        int sl = (e & 131071) >> 14;
        atomicAdd(&lcnt[node * SL + sl], 1);
    }
    __syncthreads();
    int loc[SL];
    int run = 0;
#pragma unroll
    for (int j = 0; j < SL; ++j) { loc[j] = run; run += lcnt[t * SL + j]; }
    tsum[t] = run;
    __syncthreads();
    for (int off = 1; off < BSZ; off <<= 1) {
        int a = (t >= off) ? tsum[t - off] : 0;
        __syncthreads();
        tsum[t] += a;
        __syncthreads();
    }
    int nbase = tsum[t] - run;   // exclusive over nodes
    int node = n0 + t;
    if (node < N) rowptr[node] = base + nbase;
#pragma unroll
    for (int j = 0; j < SL; ++j) lcur[t * SL + j] = nbase + loc[j];
    __syncthreads();
    for (int i = t; i < cnt; i += 512) {
        int e = staging[base + i];
        int nd = (e >> 21) & (BSZ - 1);
        int sl = (e & 131071) >> 14;
        int pos = atomicAdd(&lcur[nd * SL + sl], 1);
        packed[base + pos] = e & 0x1FFFFF;   // src | type<<17
    }
}

// ---- fused h = x @ W^T (fp16 out, node-major) + per-(node,head) scores ----
template <int OUT, int C, typename XT>
__global__ __launch_bounds__(256) void gemmscore_kernel(const XT* __restrict__ x,
                                                        const float* __restrict__ W,
                                                        const float* __restrict__ asrc,
                                                        const float* __restrict__ adst, int N,
                                                        __half* __restrict__ hout,
                                                        float* __restrict__ ssrc,
                                                        float* __restrict__ sdst) {
    __shared__ float wt[64 * (OUT + 1)];
    __shared__ float xs[32 * 64];
    int t = threadIdx.x;
    for (int idx = t; idx < OUT * 64; idx += 256) {
        int j = idx >> 6, k = idx & 63;
        wt[k * (OUT + 1) + j] = W[idx];
    }
    int rowbase = blockIdx.x * 32;
    int nrows = min(32, N - rowbase);
    for (int idx = t; idx < nrows * 64; idx += 256) xs[idx] = ldf(x, rowbase * 64 + idx);
    __syncthreads();
    int j = t % OUT;
    int rg = t / OUT;
    const int NG = 256 / OUT;
    float aj_s = asrc[j], aj_d = adst[j];
    int hd = j / C;
    for (int r = rg; r < nrows; r += NG) {
        float acc = 0.f;
        const float* xr = xs + r * 64;
#pragma unroll
        for (int k = 0; k < 64; ++k) acc += xr[k] * wt[k * (OUT + 1) + j];
        hout[(size_t)(rowbase + r) * OUT + j] = __float2half(acc);
        float ps = acc * aj_s, pd = acc * aj_d;
#pragma unroll
        for (int w = C / 2; w >= 1; w >>= 1) {
            ps += __shfl_xor(ps, w);
            pd += __shfl_xor(pd, w);
        }
        if ((j & (C - 1)) == 0) {
            int node = rowbase + r;
            ssrc[node * 4 + hd] = ps;
            sdst[node * 4 + hd] = pd;
        }
    }
}

__device__ inline void fma_h8(float* acc, float4 v, float ex) {
    const __half2* h2 = (const __half2*)&v;
#pragma unroll
    for (int i = 0; i < 4; ++i) {
        float2 f = __half22float2(h2[i]);
        acc[2 * i]     += ex * f.x;
        acc[2 * i + 1] += ex * f.y;
    }
}

// ---- online-softmax aggregate: TPN threads per node, 8 fp16 ch each ----
template <int C, int TPN, bool RELU, typename OT>
__global__ __launch_bounds__(256) void agg_kernel(const int* __restrict__ rowptr,
                                                  const int* __restrict__ packed,
                                                  const __half* __restrict__ hmat,
                                                  const float* __restrict__ ssrc,
                                                  const float* __restrict__ sdst,
                                                  const float* __restrict__ alphaE,
                                                  const float* __restrict__ bias, int N,
                                                  OT* __restrict__ out) {
    __shared__ float aE[44];
    if (threadIdx.x < 44) aE[threadIdx.x] = alphaE[threadIdx.x];
    __syncthreads();
    int t = blockIdx.x * 256 + threadIdx.x;
    if (t >= N * TPN) return;
    const int HALVES = TPN / 4;
    int node = t / TPN;
    int sub  = t % TPN;
    int hd   = sub / HALVES;
    int off  = hd * C + (sub % HALVES) * 8;
    const int ROW = 4 * C;
    int beg = rowptr[node], end = rowptr[node + 1];
    float sd = sdst[node * 4 + hd];
    float m = LRELU(ssrc[node * 4 + hd] + sd + aE[40 + hd]);
    float denom = 1.f;
    float acc[8];
    {
        float4 sv = *(const float4*)(hmat + (size_t)node * ROW + off);
#pragma unroll
        for (int c = 0; c < 8; ++c) acc[c] = 0.f;
        fma_h8(acc, sv, 1.f);
    }
    int k = beg;
    for (; k + 4 <= end; k += 4) {
        int p0 = __builtin_nontemporal_load(&packed[k]);
        int p1 = __builtin_nontemporal_load(&packed[k + 1]);
        int p2 = __builtin_nontemporal_load(&packed[k + 2]);
        int p3 = __builtin_nontemporal_load(&packed[k + 3]);
        int n0 = p0 & 131071, n1 = p1 & 131071, n2 = p2 & 131071, n3 = p3 & 131071;
        float v0 = ssrc[n0 * 4 + hd], v1 = ssrc[n1 * 4 + hd];
        float v2 = ssrc[n2 * 4 + hd], v3 = ssrc[n3 * 4 + hd];
        float4 r0 = *(const float4*)(hmat + (size_t)n0 * ROW + off);
        float4 r1 = *(const float4*)(hmat + (size_t)n1 * ROW + off);
        float4 r2 = *(const float4*)(hmat + (size_t)n2 * ROW + off);
        float4 r3 = *(const float4*)(hmat + (size_t)n3 * ROW + off);
        float a0 = LRELU(v0 + sd + aE[((p0 >> 17) & 15) * 4 + hd]);
        float a1 = LRELU(v1 + sd + aE[((p1 >> 17) & 15) * 4 + hd]);
        float a2 = LRELU(v2 + sd + aE[((p2 >> 17) & 15) * 4 + hd]);
        float a3 = LRELU(v3 + sd + aE[((p3 >> 17) & 15) * 4 + hd]);
        float mn = fmaxf(fmaxf(a0, a1), fmaxf(a2, a3));
        if (mn > m) {
            float r = __expf(m - mn);
            denom *= r;
#pragma unroll
            for (int c = 0; c < 8; ++c) acc[c] *= r;
            m = mn;
        }
        float e0 = __expf(a0 - m), e1 = __expf(a1 - m);
        float e2 = __expf(a2 - m), e3 = __expf(a3 - m);
        denom += (e0 + e1) + (e2 + e3);
        fma_h8(acc, r0, e0);
        fma_h8(acc, r1, e1);
        fma_h8(acc, r2, e2);
        fma_h8(acc, r3, e3);
    }
    for (; k < end; ++k) {
        int p0 = __builtin_nontemporal_load(&packed[k]);
        int n0 = p0 & 131071;
        float v0 = ssrc[n0 * 4 + hd];
        float4 r0 = *(const float4*)(hmat + (size_t)n0 * ROW + off);
        float a0 = LRELU(v0 + sd + aE[((p0 >> 17) & 15) * 4 + hd]);
        if (a0 > m) {
            float r = __expf(m - a0);
            denom *= r;
#pragma unroll
            for (int c = 0; c < 8; ++c) acc[c] *= r;
            m = a0;
        }
        float e0 = __expf(a0 - m);
        denom += e0;
        fma_h8(acc, r0, e0);
    }
    float inv = 1.f / denom;
    if constexpr (std::is_same<OT, __half>::value) {
        union { cfloat4 v; __half h[8]; } u;
#pragma unroll
        for (int c = 0; c < 8; ++c) {
            float a = fmaf(acc[c], inv, bias[off + c]);
            if (RELU) a = fmaxf(a, 0.f);
            u.h[c] = __float2half(a);
        }
        cfloat4* op = (cfloat4*)(out + (size_t)node * ROW + off);
        __builtin_nontemporal_store(u.v, op);
    } else {
        cfloat4 o0, o1;
#pragma unroll
        for (int c = 0; c < 4; ++c) {
            float a = fmaf(acc[c], inv, bias[off + c]);
            float bq = fmaf(acc[c + 4], inv, bias[off + c + 4]);
            if (RELU) { a = fmaxf(a, 0.f); bq = fmaxf(bq, 0.f); }
            o0[c] = a;
            o1[c] = bq;
        }
        cfloat4* op = (cfloat4*)(out + (size_t)node * ROW + off);
        __builtin_nontemporal_store(o0, op);
        __builtin_nontemporal_store(o1, op + 1);
    }
}

extern "C" void kernel_launch(void* const* d_in, const int* in_sizes, int n_in,
                              void* d_out, int out_size, void* d_ws, size_t ws_size,
                              hipStream_t stream) {
    const float* x    = (const float*)d_in[0];
    const int*   ei   = (const int*)d_in[1];
    const int*   ety  = (const int*)d_in[2];
    const float* emb  = (const float*)d_in[3];
    const float* w0   = (const float*)d_in[4];
    const float* as0  = (const float*)d_in[5];
    const float* ad0  = (const float*)d_in[6];
    const float* ae0  = (const float*)d_in[8];
    const float* b0   = (const float*)d_in[9];
    const float* w1   = (const float*)d_in[10];
    const float* as1  = (const float*)d_in[11];
    const float* ad1  = (const float*)d_in[12];
    const float* ae1  = (const float*)d_in[14];
    const float* b1   = (const float*)d_in[15];
    const float* we0  = (const float*)d_in[7];
    const float* we1  = (const float*)d_in[13];

    const int N = in_sizes[0] / 64;
    const int E = in_sizes[1] / 2;
    const int NB = (N + BSZ - 1) >> BBITS;

    char* ws = (char*)d_ws;
    size_t o = 0;
    auto alloc = [&](size_t bytes) { size_t r = o; o = (o + bytes + 255) & ~(size_t)255; return r; };
    size_t o_ctrl     = alloc(4 * 288);              // bcount[260] | counts10[16] | done[1]
    size_t o_bbase    = alloc(4 * 260);
    size_t o_bcursor  = alloc(4 * 260);
    size_t o_alphaE   = alloc(4 * 88);
    size_t o_rowptr   = alloc((size_t)4 * (N + 1));
    size_t o_staging  = alloc((size_t)4 * E);
    size_t o_packed   = alloc((size_t)4 * E);
    size_t o_h        = alloc((size_t)2 * N * 64);   // fp16 h (layer0 [N,64] / layer1 [N,32])
    size_t o_x1h      = alloc((size_t)2 * N * 64);   // fp16 layer-0 output
    size_t o_ssrc     = alloc((size_t)4 * N * 4);
    size_t o_sdst     = alloc((size_t)4 * N * 4);
    (void)ws_size;

    int*    ctrl     = (int*)(ws + o_ctrl);
    int*    bcount   = ctrl;
    int*    counts10 = ctrl + 260;
    int*    done     = ctrl + 276;
    int*    bbase    = (int*)(ws + o_bbase);
    int*    bcursor  = (int*)(ws + o_bcursor);
    float*  alphaE   = (float*)(ws + o_alphaE);
    int*    rowptr   = (int*)(ws + o_rowptr);
    int*    staging  = (int*)(ws + o_staging);
    int*    packed   = (int*)(ws + o_packed);
    __half* h0       = (__half*)(ws + o_h);
    __half* x1h      = (__half*)(ws + o_x1h);
    float*  ssrc     = (float*)(ws + o_ssrc);
    float*  sdst     = (float*)(ws + o_sdst);
    float*  outp     = (float*)d_out;

    hipMemsetAsync(ctrl, 0, 4 * 288, stream);

    int egrid = (E + 4095) / 4096;
    k1_hist_scan<<<egrid, 256, 0, stream>>>(ei, ety, E, bcount, counts10, done, NB,
                                            bbase, bcursor, rowptr, N,
                                            emb, we0, ae0, we1, ae1, alphaE);
    k3_bucket_scatter<<<egrid, 256, 0, stream>>>(ei, ety, E, bcursor, staging);
    k4_bucket_build<<<NB, 512, 0, stream>>>(bbase, staging, N, rowptr, packed);

    int ngrid32 = (N + 31) / 32;
    int agg_grid0 = (N * 8 + 255) / 256;   // TPN=8
    int agg_grid1 = (N * 4 + 255) / 256;   // TPN=4

    // Layer 0: in=64, H=4, C=16
    gemmscore_kernel<64, 16, float><<<ngrid32, 256, 0, stream>>>(x, w0, as0, ad0, N,
                                                                 h0, ssrc, sdst);
    agg_kernel<16, 8, true, __half><<<agg_grid0, 256, 0, stream>>>(rowptr, packed, h0,
                                                                   ssrc, sdst, alphaE,
                                                                   b0, N, x1h);
    // Layer 1: in=64, H=4, C=8
    gemmscore_kernel<32, 8, __half><<<ngrid32, 256, 0, stream>>>(x1h, w1, as1, ad1, N,
                                                                 h0, ssrc, sdst);
    agg_kernel<8, 4, false, float><<<agg_grid1, 256, 0, stream>>>(rowptr, packed, h0,
                                                                  ssrc, sdst, alphaE + 44,
                                                                  b1, N, outp);
}